// Round 15
// baseline (81.741 us; speedup 1.0000x reference)
//
#include <hip/hip_runtime.h>
#include <hip/hip_bf16.h>
#include <cstddef>

// x [4,256,64,64] f32 | offset [4,18,64,64] f32 | weight [256,256,3,3] f32
// out [4,256,64,64] f32 ; stride=1 pad=1 dil=1 -> Ho=Wo=64
#define B_    4
#define C_    256
#define H_    64
#define W_    64
#define CO_   256
#define K2_   9
#define NSTEP 72   // K = 2304; step s = 9*cc + tap; atoms within step = 32 channels

typedef __attribute__((ext_vector_type(8))) short short8;
typedef __attribute__((ext_vector_type(4))) float f32x4;

__device__ __forceinline__ unsigned short f2bf(float f) {
    unsigned u = __builtin_bit_cast(unsigned, f);
    u = (u + 0x7fffu + ((u >> 16) & 1u)) >> 16;   // RNE
    return (unsigned short)u;
}
__device__ __forceinline__ unsigned pack2bf(float lo, float hi) {
    __hip_bfloat162 h = __float22bfloat162_rn(make_float2(lo, hi));
    unsigned r; __builtin_memcpy(&r, &h, 4);
    return r;
}
__device__ __forceinline__ float bflo(unsigned u) {
    return __builtin_bit_cast(float, u << 16);
}
__device__ __forceinline__ float bfhi(unsigned u) {
    return __builtin_bit_cast(float, u & 0xffff0000u);
}

// bf16 pair dot: acc + x.lo*w.lo + x.hi*w.hi (v_dot2_f32_bf16 when available)
#if defined(__has_builtin)
#if __has_builtin(__builtin_amdgcn_fdot2_f32_bf16)
#define HAS_BFDOT2 1
#endif
#endif
__device__ __forceinline__ float dot2bf(unsigned x, unsigned w, float acc) {
#ifdef HAS_BFDOT2
    typedef __attribute__((ext_vector_type(2))) __bf16 bf16x2;
    return __builtin_amdgcn_fdot2_f32_bf16(__builtin_bit_cast(bf16x2, x),
                                           __builtin_bit_cast(bf16x2, w),
                                           acc, false);
#else
    return acc + bflo(x) * bflo(w) + bfhi(x) * bfhi(w);
#endif
}

// ---------------------------------------------------------------------------
// weight -> wpk[s][mt][lane][e] bf16, MFMA A-frag order, tap-major K:
// step s: cc = s/9, tap = s%9; k-atom kk -> channel c = 32cc + kk.
// A(i,k): i = lane&15 -> o = mt*16+i ; kk = 8*(lane>>4)+e.
// ---------------------------------------------------------------------------
__global__ void wpack_kernel(const float* __restrict__ w,
                             unsigned short* __restrict__ wpk) {
    const int idx = blockIdx.x * 256 + threadIdx.x;   // 72*16*64 = 73728
    if (idx >= NSTEP * 16 * 64) return;
    const int lane = idx & 63;
    const int mt   = (idx >> 6) & 15;
    const int s    = idx >> 10;
    const int o    = mt * 16 + (lane & 15);
    const int cc   = s / 9;
    const int t    = s - 9 * cc;
    const int c0   = cc * 32 + ((lane >> 4) << 3);
    unsigned short h[8];
#pragma unroll
    for (int e = 0; e < 8; ++e)
        h[e] = f2bf(w[(o * C_ + c0 + e) * K2_ + t]);
    uint4 v;
    v.x = h[0] | ((unsigned)h[1] << 16);
    v.y = h[2] | ((unsigned)h[3] << 16);
    v.z = h[4] | ((unsigned)h[5] << 16);
    v.w = h[6] | ((unsigned)h[7] << 16);
    *reinterpret_cast<uint4*>(&wpk[(size_t)idx * 8]) = v;
}

__device__ __forceinline__ short8 loadA(const unsigned short* __restrict__ wpk,
                                        const float* __restrict__ wraw,
                                        int use_pk, int s, int mt, int lane) {
    if (use_pk) {
        return *reinterpret_cast<const short8*>(
            wpk + (((size_t)(s * 16 + mt) * 64 + lane) << 3));
    } else {
        const int cc = s / 9;
        const int t  = s - 9 * cc;
        const int c0 = cc * 32 + ((lane >> 4) << 3);
        const int o  = mt * 16 + (lane & 15);
        short8 r;
#pragma unroll
        for (int e = 0; e < 8; ++e)
            r[e] = (short)f2bf(wraw[(o * C_ + c0 + e) * K2_ + t]);
        return r;
    }
}

// ---------------------------------------------------------------------------
// Block = (b, ho, wo-half): M=256 x N=32, K=2304. Grid 512 -> 2 blocks/CU.
// Window (r14-verified): per chunk, 32 ch x 11 rows x 44 pair-packed bf16
// slots, stride 1936 B, + zeroed pad; one bilinear value = 1 ds_read2_b32
// (rows +0/+176, folded weights) + 2 v_dot2_f32_bf16.
// Meta: one uint4 [w01, w23, enc, 0] per (tap,wo) -> single ds_read_b128.
// Waves 4M x 1N (r9-verified mapping): wave owns 4 M-tiles x 1 N-tile ->
// ONE col ds_read_b128 + 4 MFMA per step. A-frags (4) prefetched 1 step
// ahead in fully-unrolled loop (r12-verified cadence).
// ---------------------------------------------------------------------------
__global__ __launch_bounds__(512, 4)
void dcn_mfma_kernel(const float* __restrict__ x,
                     const float* __restrict__ off,
                     const unsigned short* __restrict__ wpk,
                     const float* __restrict__ wraw,
                     float* __restrict__ out,
                     int use_pk) {
    __shared__ __align__(16) unsigned s_win[32 * 484 + 48];        // 62144 B
    __shared__ __align__(16) uint4 s_meta[K2_ * 32];               // 4608 B
    __shared__ __align__(16) unsigned short s_colb[2][1024];       // 4096 B

    const int tid = threadIdx.x;
    const int bid = blockIdx.x;
    const int xcd  = bid & 7;
    const int slot = bid >> 3;
    const int b    = xcd >> 1;
    const int ho   = ((xcd & 1) << 5) | (slot >> 1);
    const int woh  = slot & 1;
    const int wo0  = woh << 5;

    const char* xb8 = (const char*)x + ((size_t)b << 22);

    // zero the overrun pad (stale LDS could be junk)
    if (tid < 48) s_win[32 * 484 + tid] = 0u;

    // ---- Phase 1: per-(tap,wo) meta -> LDS uint4 ---------------------------
    if (tid < K2_ * 32) {
        const int t = tid >> 5;
        const int p = tid & 31;
        const int pa = wo0 + p;
        const float dy = off[((b * 18 + 2 * t    ) * 64 + ho) * 64 + pa];
        const float dx = off[((b * 18 + 2 * t + 1) * 64 + ho) * 64 + pa];
        const float py = (float)(ho - 1 + t / 3) + dy;
        const float px = (float)(pa - 1 + t % 3) + dx;
        const float y0f = floorf(py), x0f = floorf(px);
        const float ly = py - y0f, lx = px - x0f;
        const float hy = 1.0f - ly, hx = 1.0f - lx;
        const int y0 = (int)y0f, x0 = (int)x0f;
        const int y1 = y0 + 1,   x1 = x0 + 1;
        const bool vy0 = (y0 >= 0) & (y0 < H_);
        const bool vy1 = (y1 >= 0) & (y1 < H_);
        const bool vx0 = (x0 >= 0) & (x0 < W_);
        const bool vx1 = (x1 >= 0) & (x1 < W_);
        const int yc0 = min(max(y0, 0), H_ - 1);
        const int yc1 = min(max(y1, 0), H_ - 1);
        const int xc0 = min(max(x0, 0), W_ - 1);
        const int xc1 = min(max(x1, 0), W_ - 1);
        float w00 = (vy0 && vx0) ? hy * hx : 0.0f;
        float w01 = (vy0 && vx1) ? hy * lx : 0.0f;
        float w10 = (vy1 && vx0) ? ly * hx : 0.0f;
        float w11 = (vy1 && vx1) ? ly * lx : 0.0f;
        const int dys = yc1 - yc0, dxs = xc1 - xc0;   // 0 or 1
        // fold duplicate coords so always-read neighbors carry weight 0
        if (!dxs) { w00 += w01; w01 = 0.0f; w10 += w11; w11 = 0.0f; }
        if (!dys) { w00 += w10; w10 = 0.0f; w01 += w11; w11 = 0.0f; }
        const int r0 = yc0 - (ho - 5);       // window rows ho-5..ho+5
        const int j0 = xc0 - (wo0 - 8);      // window slots wo0-8..wo0+35
        const bool fast = (r0 >= 0) & (r0 + dys <= 10) & (j0 >= 0) & (j0 <= 43);
        int enc;
        if (fast)
            enc = (r0 * 44 + j0) << 2;                 // pure slot byte offset
        else
            enc = (int)(0x80000000u
                        | (unsigned)((((yc0 << 6) + xc0) << 2) | (dys << 1) | dxs));
        uint4 m;
        m.x = pack2bf(w00, w01);
        m.y = pack2bf(w10, w11);
        m.z = (unsigned)enc;
        m.w = 0u;
        s_meta[t * 32 + p] = m;
    }

    // ---- staging source offsets (r9-verified): unit u = tid + 512v ---------
    unsigned stoff[8];
#pragma unroll
    for (int v = 0; v < 8; ++v) {
        const int u = tid + (v << 9);
        if (u < 3872) {
            const int cl  = u / 121;
            const int rem = u - cl * 121;
            const int r   = rem / 11;
            const int q   = rem - r * 11;
            const int y   = ho - 5 + r;
            int gof = (((y << 6) + wo0 - 8) << 2) + (q << 4);
            gof = min(max(gof, 0), 16368);
            if ((unsigned)y >= 64u) gof = 0;          // garbage row, never read
            stoff[v] = ((unsigned)cl << 14) + (unsigned)gof;
        } else {
            stoff[v] = 0xffffffffu;
        }
    }

    const int lane = tid & 63;
    const int wave = tid >> 6;
    const int wo   = lane & 31;
    const int kk0  = (wave << 2) | ((lane >> 5) << 1);  // staging channels kk0,kk0+1
    const unsigned swr = ((unsigned)(wo >> 4) << 10)
                       | ((unsigned)((wo & 15) | ((kk0 >> 3) << 4)) << 4)
                       | ((unsigned)(kk0 & 7) << 1);
    const int mt0  = (wave >> 1) << 2;                  // 4 M-tiles per wave
    const unsigned brd = ((unsigned)(wave & 1) << 10) | ((unsigned)lane << 4);
    const char* winC = (const char*)s_win + kk0 * 1936; // 484 slots/channel
    const char* winD = winC + 1936;                     // channel kk0+1

    f32x4 acc[4];
#pragma unroll
    for (int m = 0; m < 4; ++m) acc[m] = (f32x4)(0.0f);

#define STAGEW(XCB_) do {                                                      \
        char* wb_ = (char*)s_win + (size_t)tid * 16;                           \
        _Pragma("unroll")                                                      \
        for (int v_ = 0; v_ < 8; ++v_) {                                       \
            const unsigned so_ = stoff[v_];                                    \
            if (so_ != 0xffffffffu) {                                          \
                const float4 g_ = *(const float4*)((XCB_) + so_);              \
                const unsigned in_ = so_ & 16383u;                             \
                const float g4_ = *(const float*)((XCB_)                       \
                                    + (in_ >= 16368u ? so_ : so_ + 16));       \
                uint4 pk_;                                                     \
                pk_.x = pack2bf(g_.x, g_.y);                                   \
                pk_.y = pack2bf(g_.y, g_.z);                                   \
                pk_.z = pack2bf(g_.z, g_.w);                                   \
                pk_.w = pack2bf(g_.w, g4_);                                    \
                *(uint4*)(wb_ + v_ * 8192) = pk_;                              \
            }                                                                  \
        }                                                                      \
    } while (0)

    // one col value pair (channels kk0, kk0+1) for tap T_ -> buffer BUFB_
    // fast path: 1 ds_read_b128 meta + 2 ds_read2_b32 window + 4 dot2
#define COLT1(T_, BUFB_, XCB_) do {                                            \
        const uint4 m_ = s_meta[(T_) * 32 + wo];                               \
        const unsigned u01_ = m_.x;                                            \
        const unsigned u23_ = m_.y;                                            \
        const int mb_ = (int)m_.z;                                             \
        float vA_, vB_;                                                        \
        if (__builtin_expect(mb_ >= 0, 1)) {                                   \
            const char* pA_ = winC + mb_;                                      \
            const char* pB_ = winD + mb_;                                      \
            const unsigned a0_ = *(const unsigned*)(pA_);                      \
            const unsigned a1_ = *(const unsigned*)(pA_ + 176);                \
            const unsigned c0_ = *(const unsigned*)(pB_);                      \
            const unsigned c1_ = *(const unsigned*)(pB_ + 176);                \
            vA_ = dot2bf(a1_, u23_, dot2bf(a0_, u01_, 0.0f));                  \
            vB_ = dot2bf(c1_, u23_, dot2bf(c0_, u01_, 0.0f));                  \
        } else {                                                               \
            const float w0_ = bflo(u01_), w1_ = bfhi(u01_);                    \
            const float w2_ = bflo(u23_), w3_ = bfhi(u23_);                    \
            const int dxb_ = (mb_ & 1) << 2, dyb_ = (mb_ & 2) << 7;            \
            const int o_ = mb_ & 0x3fffc;                                      \
            const char* plA_ = (XCB_) + ((size_t)kk0 << 14);                   \
            const char* plB_ = plA_ + (1 << 14);                               \
            vA_ = w0_ * *(const float*)(plA_ + o_)                             \
                + w1_ * *(const float*)(plA_ + o_ + dxb_)                      \
                + w2_ * *(const float*)(plA_ + o_ + dyb_)                      \
                + w3_ * *(const float*)(plA_ + o_ + dyb_ + dxb_);              \
            vB_ = w0_ * *(const float*)(plB_ + o_)                             \
                + w1_ * *(const float*)(plB_ + o_ + dxb_)                      \
                + w2_ * *(const float*)(plB_ + o_ + dyb_)                      \
                + w3_ * *(const float*)(plB_ + o_ + dyb_ + dxb_);              \
        }                                                                      \
        *(unsigned*)((char*)(BUFB_) + swr) = pack2bf(vA_, vB_);                \
    } while (0)

#define MFMA_(A_, B_, C_) __builtin_amdgcn_mfma_f32_16x16x32_bf16(A_, B_, C_, 0, 0, 0)

#define GEMM4(BUFB_) do {                                                      \
        const short8 bb_ = *(const short8*)((const char*)(BUFB_) + brd);       \
        acc[0] = MFMA_(aC0, bb_, acc[0]);                                      \
        acc[1] = MFMA_(aC1, bb_, acc[1]);                                      \
        acc[2] = MFMA_(aC2, bb_, acc[2]);                                      \
        acc[3] = MFMA_(aC3, bb_, acc[3]);                                      \
    } while (0)

#define BARLG() do {                                                           \
        asm volatile("s_waitcnt lgkmcnt(0)" ::: "memory");                     \
        __builtin_amdgcn_s_barrier();                                          \
    } while (0)

    char* const buf0 = (char*)s_colb;
    char* const buf1 = (char*)s_colb + 2048;

    // ---- Prologue ----------------------------------------------------------
    STAGEW(xb8);                       // chunk 0 window
    __syncthreads();                   // pad + meta + window visible
    COLT1(0, buf0, xb8);               // col(step 0) -> buf0
    short8 aC0 = loadA(wpk, wraw, use_pk, 0, mt0,     lane);
    short8 aC1 = loadA(wpk, wraw, use_pk, 0, mt0 + 1, lane);
    short8 aC2 = loadA(wpk, wraw, use_pk, 0, mt0 + 2, lane);
    short8 aC3 = loadA(wpk, wraw, use_pk, 0, mt0 + 3, lane);
    BARLG();

    // ---- Main loop: 8 chunks x 9 per-step-barrier steps (unrolled) --------
    for (int cc = 0; cc < 8; ++cc) {
        const char* xcb  = xb8 + ((size_t)cc << 19);
        const char* xcbN = xb8 + ((size_t)(cc + 1) << 19);

#pragma unroll
        for (int j = 0; j < 9; ++j) {
            const int sj = cc * 9 + j;
            short8 aN0, aN1, aN2, aN3;
            const bool pf = (sj + 1 < NSTEP);
            if (pf) {                                  // prefetch next-step A
                aN0 = loadA(wpk, wraw, use_pk, sj + 1, mt0,     lane);
                aN1 = loadA(wpk, wraw, use_pk, sj + 1, mt0 + 1, lane);
                aN2 = loadA(wpk, wraw, use_pk, sj + 1, mt0 + 2, lane);
                aN3 = loadA(wpk, wraw, use_pk, sj + 1, mt0 + 3, lane);
            }
            if (j < 8) COLT1(j + 1, (j & 1) ? buf0 : buf1, xcb);  // col(s+1)
            GEMM4((j & 1) ? buf1 : buf0);              // col(s)
            BARLG();
            if (pf) { aC0 = aN0; aC1 = aN1; aC2 = aN2; aC3 = aN3; }
        }

        if (cc < 7) {                                  // next chunk window+col0
            STAGEW(xcbN);
            __syncthreads();
            COLT1(0, buf0, xcbN);
            BARLG();
        }
    }

#undef STAGEW
#undef COLT1
#undef MFMA_
#undef GEMM4
#undef BARLG

    // ---- Epilogue (r9-verified 4Mx1N): row = 4*(lane>>4)+r, col = lane&15 --
    const int ncol = wo0 + ((wave & 1) << 4) + (lane & 15);
#pragma unroll
    for (int m = 0; m < 4; ++m) {
        const int ob = (mt0 + m) * 16 + ((lane >> 4) << 2);
#pragma unroll
        for (int r = 0; r < 4; ++r) {
            out[(((size_t)(b * CO_ + ob + r) * 64 + ho) << 6) + ncol] = acc[m][r];
        }
    }
}

// ---------------------------------------------------------------------------
extern "C" void kernel_launch(void* const* d_in, const int* in_sizes, int n_in,
                              void* d_out, int out_size, void* d_ws, size_t ws_size,
                              hipStream_t stream) {
    const float* x      = (const float*)d_in[0];
    const float* offset = (const float*)d_in[1];
    const float* weight = (const float*)d_in[2];
    float* out = (float*)d_out;

    const size_t pk_bytes = (size_t)NSTEP * 16 * 64 * 8 * 2;  // 1,179,648 B
    const int use_pk = (ws_size >= pk_bytes) ? 1 : 0;
    unsigned short* wpk = (unsigned short*)d_ws;

    if (use_pk) {
        wpack_kernel<<<288, 256, 0, stream>>>(weight, wpk);
    }
    dcn_mfma_kernel<<<512, 512, 0, stream>>>(x, offset, wpk, weight, out, use_pk);
}

// Round 16
// 65.737 us; speedup vs baseline: 1.2435x; 1.2435x over previous
//
#include <hip/hip_runtime.h>
#include <hip/hip_bf16.h>
#include <cstddef>

// x [4,256,64,64] f32 | offset [4,18,64,64] f32 | weight [256,256,3,3] f32
// out [4,256,64,64] f32 ; stride=1 pad=1 dil=1 -> Ho=Wo=64
#define B_    4
#define C_    256
#define H_    64
#define W_    64
#define CO_   256
#define K2_   9
#define NSTEP 72   // K = 2304; step s = 9*cc + tap; atoms within step = 32 channels

typedef __attribute__((ext_vector_type(8))) short short8;
typedef __attribute__((ext_vector_type(4))) float f32x4;

__device__ __forceinline__ unsigned short f2bf(float f) {
    unsigned u = __builtin_bit_cast(unsigned, f);
    u = (u + 0x7fffu + ((u >> 16) & 1u)) >> 16;   // RNE
    return (unsigned short)u;
}
__device__ __forceinline__ unsigned pack2bf(float lo, float hi) {
    __hip_bfloat162 h = __float22bfloat162_rn(make_float2(lo, hi));
    unsigned r; __builtin_memcpy(&r, &h, 4);
    return r;
}
__device__ __forceinline__ float bflo(unsigned u) {
    return __builtin_bit_cast(float, u << 16);
}
__device__ __forceinline__ float bfhi(unsigned u) {
    return __builtin_bit_cast(float, u & 0xffff0000u);
}

// bf16 pair dot: acc + x.lo*w.lo + x.hi*w.hi (v_dot2_f32_bf16 when available)
#if defined(__has_builtin)
#if __has_builtin(__builtin_amdgcn_fdot2_f32_bf16)
#define HAS_BFDOT2 1
#endif
#endif
__device__ __forceinline__ float dot2bf(unsigned x, unsigned w, float acc) {
#ifdef HAS_BFDOT2
    typedef __attribute__((ext_vector_type(2))) __bf16 bf16x2;
    return __builtin_amdgcn_fdot2_f32_bf16(__builtin_bit_cast(bf16x2, x),
                                           __builtin_bit_cast(bf16x2, w),
                                           acc, false);
#else
    return acc + bflo(x) * bflo(w) + bfhi(x) * bfhi(w);
#endif
}

// ---------------------------------------------------------------------------
// weight -> wpk[s][mt][lane][e] bf16, MFMA A-frag order, tap-major K:
// step s: cc = s/9, tap = s%9; k-atom kk -> channel c = 32cc + kk.
// A(i,k): i = lane&15 -> o = mt*16+i ; kk = 8*(lane>>4)+e.
// ---------------------------------------------------------------------------
__global__ void wpack_kernel(const float* __restrict__ w,
                             unsigned short* __restrict__ wpk) {
    const int idx = blockIdx.x * 256 + threadIdx.x;   // 72*16*64 = 73728
    if (idx >= NSTEP * 16 * 64) return;
    const int lane = idx & 63;
    const int mt   = (idx >> 6) & 15;
    const int s    = idx >> 10;
    const int o    = mt * 16 + (lane & 15);
    const int cc   = s / 9;
    const int t    = s - 9 * cc;
    const int c0   = cc * 32 + ((lane >> 4) << 3);
    unsigned short h[8];
#pragma unroll
    for (int e = 0; e < 8; ++e)
        h[e] = f2bf(w[(o * C_ + c0 + e) * K2_ + t]);
    uint4 v;
    v.x = h[0] | ((unsigned)h[1] << 16);
    v.y = h[2] | ((unsigned)h[3] << 16);
    v.z = h[4] | ((unsigned)h[5] << 16);
    v.w = h[6] | ((unsigned)h[7] << 16);
    *reinterpret_cast<uint4*>(&wpk[(size_t)idx * 8]) = v;
}

__device__ __forceinline__ short8 loadA(const unsigned short* __restrict__ wpk,
                                        const float* __restrict__ wraw,
                                        int use_pk, int s, int mt, int lane) {
    if (use_pk) {
        return *reinterpret_cast<const short8*>(
            wpk + (((size_t)(s * 16 + mt) * 64 + lane) << 3));
    } else {
        const int cc = s / 9;
        const int t  = s - 9 * cc;
        const int c0 = cc * 32 + ((lane >> 4) << 3);
        const int o  = mt * 16 + (lane & 15);
        short8 r;
#pragma unroll
        for (int e = 0; e < 8; ++e)
            r[e] = (short)f2bf(wraw[(o * C_ + c0 + e) * K2_ + t]);
        return r;
    }
}

// ---------------------------------------------------------------------------
// Block = (b, ho, wo-half): M=256 x N=32, K=2304. Grid 512 -> 2 blocks/CU.
// Window (r14-verified): per chunk, 32 ch x 11 rows x 44 pair-packed bf16
// slots, stride 1936 B, + zeroed pad; one bilinear value = 1 ds_read2_b32
// (rows +0/+176, folded weights) + 2 v_dot2_f32_bf16. Meta LDS SoA.
// Waves 2M x 2N (r14-verified). 3-tap phases (r9-verified rotation):
// 4 barriers/chunk (~33 total vs r14's 88). A-loads hoisted to phase start
// (phase-local, die before barrier -> no r15-style spill; COLT LDS chain
// hides their L2 latency).
// ---------------------------------------------------------------------------
__global__ __launch_bounds__(512, 4)
void dcn_mfma_kernel(const float* __restrict__ x,
                     const float* __restrict__ off,
                     const unsigned short* __restrict__ wpk,
                     const float* __restrict__ wraw,
                     float* __restrict__ out,
                     int use_pk) {
    __shared__ __align__(16) unsigned s_win[32 * 484 + 48];        // 62144 B
    __shared__ __align__(8)  unsigned s_mwp[K2_ * 32 * 2];         // 2304 B
    __shared__ int s_menc[K2_ * 32];                               // 1152 B
    __shared__ __align__(16) unsigned short s_colb[2][3][1024];    // 12288 B

    const int tid = threadIdx.x;
    const int bid = blockIdx.x;
    const int xcd  = bid & 7;
    const int slot = bid >> 3;
    const int b    = xcd >> 1;
    const int ho   = ((xcd & 1) << 5) | (slot >> 1);
    const int woh  = slot & 1;
    const int wo0  = woh << 5;

    const char* xb8 = (const char*)x + ((size_t)b << 22);

    // zero the overrun pad (stale LDS could be junk)
    if (tid < 48) s_win[32 * 484 + tid] = 0u;

    // ---- Phase 1: per-(tap,wo) meta -> LDS SoA ----------------------------
    if (tid < K2_ * 32) {
        const int t = tid >> 5;
        const int p = tid & 31;
        const int pa = wo0 + p;
        const float dy = off[((b * 18 + 2 * t    ) * 64 + ho) * 64 + pa];
        const float dx = off[((b * 18 + 2 * t + 1) * 64 + ho) * 64 + pa];
        const float py = (float)(ho - 1 + t / 3) + dy;
        const float px = (float)(pa - 1 + t % 3) + dx;
        const float y0f = floorf(py), x0f = floorf(px);
        const float ly = py - y0f, lx = px - x0f;
        const float hy = 1.0f - ly, hx = 1.0f - lx;
        const int y0 = (int)y0f, x0 = (int)x0f;
        const int y1 = y0 + 1,   x1 = x0 + 1;
        const bool vy0 = (y0 >= 0) & (y0 < H_);
        const bool vy1 = (y1 >= 0) & (y1 < H_);
        const bool vx0 = (x0 >= 0) & (x0 < W_);
        const bool vx1 = (x1 >= 0) & (x1 < W_);
        const int yc0 = min(max(y0, 0), H_ - 1);
        const int yc1 = min(max(y1, 0), H_ - 1);
        const int xc0 = min(max(x0, 0), W_ - 1);
        const int xc1 = min(max(x1, 0), W_ - 1);
        float w00 = (vy0 && vx0) ? hy * hx : 0.0f;
        float w01 = (vy0 && vx1) ? hy * lx : 0.0f;
        float w10 = (vy1 && vx0) ? ly * hx : 0.0f;
        float w11 = (vy1 && vx1) ? ly * lx : 0.0f;
        const int dys = yc1 - yc0, dxs = xc1 - xc0;   // 0 or 1
        // fold duplicate coords so always-read neighbors carry weight 0
        if (!dxs) { w00 += w01; w01 = 0.0f; w10 += w11; w11 = 0.0f; }
        if (!dys) { w00 += w10; w10 = 0.0f; w01 += w11; w11 = 0.0f; }
        const int r0 = yc0 - (ho - 5);       // window rows ho-5..ho+5
        const int j0 = xc0 - (wo0 - 8);      // window slots wo0-8..wo0+35
        const bool fast = (r0 >= 0) & (r0 + dys <= 10) & (j0 >= 0) & (j0 <= 43);
        int enc;
        if (fast)
            enc = (r0 * 44 + j0) << 2;                 // pure slot byte offset
        else
            enc = (int)(0x80000000u
                        | (unsigned)((((yc0 << 6) + xc0) << 2) | (dys << 1) | dxs));
        s_mwp[(t * 32 + p) * 2    ] = pack2bf(w00, w01);
        s_mwp[(t * 32 + p) * 2 + 1] = pack2bf(w10, w11);
        s_menc[t * 32 + p] = enc;
    }

    // ---- staging source offsets (r9-verified): unit u = tid + 512v ---------
    unsigned stoff[8];
#pragma unroll
    for (int v = 0; v < 8; ++v) {
        const int u = tid + (v << 9);
        if (u < 3872) {
            const int cl  = u / 121;
            const int rem = u - cl * 121;
            const int r   = rem / 11;
            const int q   = rem - r * 11;
            const int y   = ho - 5 + r;
            int gof = (((y << 6) + wo0 - 8) << 2) + (q << 4);
            gof = min(max(gof, 0), 16368);
            if ((unsigned)y >= 64u) gof = 0;          // garbage row, never read
            stoff[v] = ((unsigned)cl << 14) + (unsigned)gof;
        } else {
            stoff[v] = 0xffffffffu;
        }
    }

    const int lane = tid & 63;
    const int wave = tid >> 6;
    const int wo   = lane & 31;
    const int kk0  = (wave << 2) | ((lane >> 5) << 1);  // staging channels kk0,kk0+1
    const unsigned swr = ((unsigned)(wo >> 4) << 10)
                       | ((unsigned)((wo & 15) | ((kk0 >> 3) << 4)) << 4)
                       | ((unsigned)(kk0 & 7) << 1);
    const unsigned brd = (unsigned)lane << 4;
    const int mt0 = wave << 1;                          // 2 M-tiles per wave
    const char* winC = (const char*)s_win + kk0 * 1936; // 484 slots/channel
    const char* winD = winC + 1936;                     // channel kk0+1

    f32x4 acc[2][2];
#pragma unroll
    for (int m = 0; m < 2; ++m)
#pragma unroll
        for (int nt = 0; nt < 2; ++nt)
            acc[m][nt] = (f32x4)(0.0f);

#define STAGEW(XCB_) do {                                                      \
        char* wb_ = (char*)s_win + (size_t)tid * 16;                           \
        _Pragma("unroll")                                                      \
        for (int v_ = 0; v_ < 8; ++v_) {                                       \
            const unsigned so_ = stoff[v_];                                    \
            if (so_ != 0xffffffffu) {                                          \
                const float4 g_ = *(const float4*)((XCB_) + so_);              \
                const unsigned in_ = so_ & 16383u;                             \
                const float g4_ = *(const float*)((XCB_)                       \
                                    + (in_ >= 16368u ? so_ : so_ + 16));       \
                uint4 pk_;                                                     \
                pk_.x = pack2bf(g_.x, g_.y);                                   \
                pk_.y = pack2bf(g_.y, g_.z);                                   \
                pk_.z = pack2bf(g_.z, g_.w);                                   \
                pk_.w = pack2bf(g_.w, g4_);                                    \
                *(uint4*)(wb_ + v_ * 8192) = pk_;                              \
            }                                                                  \
        }                                                                      \
    } while (0)

    // one col value pair (channels kk0, kk0+1) for tap T_ -> slot base DST_
    // fast path: 2x ds_read2_b32 (rows +0/+176) + 4x dot2
#define COLT1(T_, DST_, XCB_) do {                                             \
        const unsigned u01_ = s_mwp[((T_) * 32 + wo) * 2];                     \
        const unsigned u23_ = s_mwp[((T_) * 32 + wo) * 2 + 1];                 \
        const int mb_ = s_menc[(T_) * 32 + wo];                                \
        float vA_, vB_;                                                        \
        if (__builtin_expect(mb_ >= 0, 1)) {                                   \
            const char* pA_ = winC + mb_;                                      \
            const char* pB_ = winD + mb_;                                      \
            const unsigned a0_ = *(const unsigned*)(pA_);                      \
            const unsigned a1_ = *(const unsigned*)(pA_ + 176);                \
            const unsigned c0_ = *(const unsigned*)(pB_);                      \
            const unsigned c1_ = *(const unsigned*)(pB_ + 176);                \
            vA_ = dot2bf(a1_, u23_, dot2bf(a0_, u01_, 0.0f));                  \
            vB_ = dot2bf(c1_, u23_, dot2bf(c0_, u01_, 0.0f));                  \
        } else {                                                               \
            const float w0_ = bflo(u01_), w1_ = bfhi(u01_);                    \
            const float w2_ = bflo(u23_), w3_ = bfhi(u23_);                    \
            const int dxb_ = (mb_ & 1) << 2, dyb_ = (mb_ & 2) << 7;            \
            const int o_ = mb_ & 0x3fffc;                                      \
            const char* plA_ = (XCB_) + ((size_t)kk0 << 14);                   \
            const char* plB_ = plA_ + (1 << 14);                               \
            vA_ = w0_ * *(const float*)(plA_ + o_)                             \
                + w1_ * *(const float*)(plA_ + o_ + dxb_)                      \
                + w2_ * *(const float*)(plA_ + o_ + dyb_)                      \
                + w3_ * *(const float*)(plA_ + o_ + dyb_ + dxb_);              \
            vB_ = w0_ * *(const float*)(plB_ + o_)                             \
                + w1_ * *(const float*)(plB_ + o_ + dxb_)                      \
                + w2_ * *(const float*)(plB_ + o_ + dyb_)                      \
                + w3_ * *(const float*)(plB_ + o_ + dyb_ + dxb_);              \
        }                                                                      \
        *(unsigned*)((char*)(DST_) + swr) = pack2bf(vA_, vB_);                 \
    } while (0)

#define MFMA_(A_, B_, C_) __builtin_amdgcn_mfma_f32_16x16x32_bf16(A_, B_, C_, 0, 0, 0)

#define GEMM22(SLOT_, A0_, A1_) do {                                           \
        const char* cb_ = (const char*)(SLOT_);                                \
        const short8 b0_ = *(const short8*)(cb_ + brd);                        \
        const short8 b1_ = *(const short8*)(cb_ + brd + 1024);                 \
        acc[0][0] = MFMA_(A0_, b0_, acc[0][0]);                                \
        acc[0][1] = MFMA_(A0_, b1_, acc[0][1]);                                \
        acc[1][0] = MFMA_(A1_, b0_, acc[1][0]);                                \
        acc[1][1] = MFMA_(A1_, b1_, acc[1][1]);                                \
    } while (0)

#define BARLG() do {                                                           \
        asm volatile("s_waitcnt lgkmcnt(0)" ::: "memory");                     \
        __builtin_amdgcn_s_barrier();                                          \
    } while (0)

    // phase: hoisted A loads (6, phase-local) -> COLT x3 -> GEMM x3 -> barrier
#define PHASE3(TC_, CDST_, TG_, GSRC_, XCB_) do {                              \
        const short8 a00_ = loadA(wpk, wraw, use_pk, s0 + (TG_),     mt0,     lane); \
        const short8 a01_ = loadA(wpk, wraw, use_pk, s0 + (TG_),     mt0 + 1, lane); \
        const short8 a10_ = loadA(wpk, wraw, use_pk, s0 + (TG_) + 1, mt0,     lane); \
        const short8 a11_ = loadA(wpk, wraw, use_pk, s0 + (TG_) + 1, mt0 + 1, lane); \
        const short8 a20_ = loadA(wpk, wraw, use_pk, s0 + (TG_) + 2, mt0,     lane); \
        const short8 a21_ = loadA(wpk, wraw, use_pk, s0 + (TG_) + 2, mt0 + 1, lane); \
        COLT1((TC_),     (char*)(CDST_),        XCB_);                         \
        COLT1((TC_) + 1, (char*)(CDST_) + 2048, XCB_);                         \
        COLT1((TC_) + 2, (char*)(CDST_) + 4096, XCB_);                         \
        GEMM22((char*)(GSRC_),        a00_, a01_);                             \
        GEMM22((char*)(GSRC_) + 2048, a10_, a11_);                             \
        GEMM22((char*)(GSRC_) + 4096, a20_, a21_);                             \
        BARLG();                                                               \
    } while (0)

    // ---- Prologue ----------------------------------------------------------
    STAGEW(xb8);                       // chunk 0 window
    __syncthreads();                   // pad + meta + window visible
    COLT1(0, (char*)s_colb,        xb8);   // chunk 0 taps 0-2 -> P(cc=0)
    COLT1(1, (char*)s_colb + 2048, xb8);
    COLT1(2, (char*)s_colb + 4096, xb8);
    BARLG();

    // ---- Main loop: 8 chunks x {PA, PB, PC, PD} ----------------------------
    for (int cc = 0; cc < 8; ++cc) {
        const char* xcb  = xb8 + ((size_t)cc << 19);
        const char* xcbN = xb8 + ((size_t)(cc + 1) << 19);
        char* bufP = (char*)s_colb + (cc & 1) * 6144;
        char* bufQ = (char*)s_colb + ((cc & 1) ^ 1) * 6144;
        const int s0 = cc * 9;

        // PA: col taps 3-5 -> Q ; GEMM taps 0-2 from P
        PHASE3(3, bufQ, 0, bufP, xcb);

        // PB: col taps 6-8 -> P ; GEMM taps 3-5 from Q
        PHASE3(6, bufP, 3, bufQ, xcb);

        // PC: stage next window ; GEMM taps 6-8 from P
        {
            const short8 a00_ = loadA(wpk, wraw, use_pk, s0 + 6, mt0,     lane);
            const short8 a01_ = loadA(wpk, wraw, use_pk, s0 + 6, mt0 + 1, lane);
            const short8 a10_ = loadA(wpk, wraw, use_pk, s0 + 7, mt0,     lane);
            const short8 a11_ = loadA(wpk, wraw, use_pk, s0 + 7, mt0 + 1, lane);
            const short8 a20_ = loadA(wpk, wraw, use_pk, s0 + 8, mt0,     lane);
            const short8 a21_ = loadA(wpk, wraw, use_pk, s0 + 8, mt0 + 1, lane);
            if (cc < 7) STAGEW(xcbN);
            GEMM22(bufP,        a00_, a01_);
            GEMM22(bufP + 2048, a10_, a11_);
            GEMM22(bufP + 4096, a20_, a21_);
            BARLG();
        }

        // PD (thin): col next-chunk taps 0-2 -> Q
        if (cc < 7) {
            COLT1(0, bufQ,        xcbN);
            COLT1(1, bufQ + 2048, xcbN);
            COLT1(2, bufQ + 4096, xcbN);
            BARLG();
        }
    }

#undef STAGEW
#undef COLT1
#undef MFMA_
#undef GEMM22
#undef BARLG
#undef PHASE3

    // ---- Epilogue: D(i,j): row = 4*(lane>>4)+r, col = lane&15 --------------
#pragma unroll
    for (int m = 0; m < 2; ++m) {
        const int ob = (mt0 + m) * 16 + ((lane >> 4) << 2);
#pragma unroll
        for (int r = 0; r < 4; ++r) {
            float* orow = out + (((size_t)(b * CO_ + ob + r) * 64 + ho) * 64 + wo0);
#pragma unroll
            for (int nt = 0; nt < 2; ++nt)
                orow[(nt << 4) | (lane & 15)] = acc[m][nt][r];
        }
    }
}

// ---------------------------------------------------------------------------
extern "C" void kernel_launch(void* const* d_in, const int* in_sizes, int n_in,
                              void* d_out, int out_size, void* d_ws, size_t ws_size,
                              hipStream_t stream) {
    const float* x      = (const float*)d_in[0];
    const float* offset = (const float*)d_in[1];
    const float* weight = (const float*)d_in[2];
    float* out = (float*)d_out;

    const size_t pk_bytes = (size_t)NSTEP * 16 * 64 * 8 * 2;  // 1,179,648 B
    const int use_pk = (ws_size >= pk_bytes) ? 1 : 0;
    unsigned short* wpk = (unsigned short*)d_ws;

    if (use_pk) {
        wpack_kernel<<<288, 256, 0, stream>>>(weight, wpk);
    }
    dcn_mfma_kernel<<<512, 512, 0, stream>>>(x, offset, wpk, weight, out, use_pk);
}